// Round 1
// baseline (86.108 us; speedup 1.0000x reference)
//
#include <hip/hip_runtime.h>
#include <math.h>

#define NH 512
#define NW 512
#define NC 2048            // 2H + 2W
#define NB 4
#define NS 4096
#define INV_TEMP (1.0f / 256.0f)
#define CL 32              // chunk length
#define NCH (NS / CL)      // 128 chunks per batch

// ---------------------------------------------------------------------------
// Phase 1a: per-chunk local suffix scan (zero-initialized carry).
// chunkSum[b,k,c] = sum_{s' in chunk k} a[b,s',c] * exp(-(t[s'] - t[k*CL])/TEMP)
// One block per (b,k); 256 threads own the 2048 channels (8 each).
// ---------------------------------------------------------------------------
__global__ __launch_bounds__(256) void tdl_chunksum_kernel(
    const float* __restrict__ target, float* __restrict__ csum)
{
    const int blk = blockIdx.x;
    const int b = blk >> 7;          // / NCH
    const int k = blk & (NCH - 1);
    const int s0 = k * CL;
    const int tid = threadIdx.x;

    __shared__ float sh_t[CL + 1];
    __shared__ float sh_dec[CL];
    __shared__ int   sh_h[CL];
    __shared__ int   sh_w[CL];
    __shared__ float sh_p[CL];

    if (tid <= CL) {
        int s = s0 + tid;
        sh_t[tid] = (s < NS) ? target[((size_t)b * NS + s) * 4] : 0.0f;
    }
    if (tid < CL) {
        const float* tg = target + ((size_t)b * NS + s0 + tid) * 4;
        sh_h[tid] = (int)tg[1];
        sh_w[tid] = (int)tg[2];
        sh_p[tid] = tg[3];
    }
    __syncthreads();
    if (tid < CL) {
        int s = s0 + tid;
        sh_dec[tid] = (s == NS - 1) ? 0.0f
                     : __expf(-(sh_t[tid + 1] - sh_t[tid]) * INV_TEMP);
    }
    __syncthreads();

    const int wv = tid >> 6;         // wave -> segment (0..3)
    const int ln = tid & 63;
    const int cbase = wv * 512 + ln * 8;

    float v[8];
#pragma unroll
    for (int j = 0; j < 8; ++j) v[j] = 0.0f;

    for (int i = CL - 1; i >= 0; --i) {
        const float d   = sh_dec[i];
        const float pv  = sh_p[i];
        const int   loc = ((wv < 2) ? sh_h[i] : sh_w[i]) - cbase;
        const float amt = ((wv & 1) == 0) ? (1.0f - pv) : pv;
#pragma unroll
        for (int j = 0; j < 8; ++j)
            v[j] = v[j] * d + ((loc == j) ? amt : 0.0f);
    }

    float* out = csum + (size_t)blk * NC + cbase;
    float4* o4 = (float4*)out;
    o4[0] = make_float4(v[0], v[1], v[2], v[3]);
    o4[1] = make_float4(v[4], v[5], v[6], v[7]);
}

// ---------------------------------------------------------------------------
// Phase 1b: cross-chunk reverse scan, IN PLACE on csum.
// After this, csum[b,k,c] = r[b, k*CL, c]  (full suffix value at chunk start).
// alpha_k = exp(-(T_{k+1} - T_k)/TEMP) telescopes the per-step decays.
// One thread per (b,c): 8192 threads = 32 blocks.
// ---------------------------------------------------------------------------
__global__ __launch_bounds__(256) void tdl_chunkscan_kernel(
    const float* __restrict__ target, float* __restrict__ csum)
{
    const int gtid = blockIdx.x * 256 + threadIdx.x;   // [0, NB*NC)
    const int b = gtid / NC;
    const int c = gtid % NC;

    float carry = 0.0f;
    for (int k = NCH - 1; k >= 0; --k) {
        float alpha = 0.0f;
        if (k < NCH - 1) {
            float t0 = target[((size_t)b * NS + k * CL) * 4];
            float t1 = target[((size_t)b * NS + (k + 1) * CL) * 4];
            alpha = __expf(-(t1 - t0) * INV_TEMP);
        }
        size_t idx = ((size_t)(b * NCH + k)) * NC + c;
        carry = csum[idx] + alpha * carry;
        csum[idx] = carry;
    }
}

// ---------------------------------------------------------------------------
// Phase 2: fused scan + soft-CE loss. One block per (b,k); each block
// re-derives r[s] for its 32 s-values (init carry = r at next chunk start),
// and computes the 4 segment losses wave-locally (wave w <-> segment w).
//   lseg = lse(pred_seg) - dot(softmax(r_seg), pred_seg)
//   loss_s = (lH0+lW0)*(1-p) + (lH1+lW1)*p
// ---------------------------------------------------------------------------
__global__ __launch_bounds__(256) void tdl_loss_kernel(
    const float* __restrict__ pred, const float* __restrict__ target,
    const float* __restrict__ csum, float* __restrict__ out)
{
    const int blk = blockIdx.x;
    const int b = blk >> 7;
    const int k = blk & (NCH - 1);
    const int s0 = k * CL;
    const int tid = threadIdx.x;

    __shared__ float sh_t[CL + 1];
    __shared__ float sh_dec[CL];
    __shared__ int   sh_h[CL];
    __shared__ int   sh_w[CL];
    __shared__ float sh_p[CL];
    __shared__ float sh_part[4];

    if (tid <= CL) {
        int s = s0 + tid;
        sh_t[tid] = (s < NS) ? target[((size_t)b * NS + s) * 4] : 0.0f;
    }
    if (tid < CL) {
        const float* tg = target + ((size_t)b * NS + s0 + tid) * 4;
        sh_h[tid] = (int)tg[1];
        sh_w[tid] = (int)tg[2];
        sh_p[tid] = tg[3];
    }
    __syncthreads();
    if (tid < CL) {
        int s = s0 + tid;
        sh_dec[tid] = (s == NS - 1) ? 0.0f
                     : __expf(-(sh_t[tid + 1] - sh_t[tid]) * INV_TEMP);
    }
    __syncthreads();

    const int wv = tid >> 6;
    const int ln = tid & 63;
    const int cbase = wv * 512 + ln * 8;

    // init carry = r[b, (k+1)*CL, :] (zero for the last chunk)
    float v[8];
    if (k == NCH - 1) {
#pragma unroll
        for (int j = 0; j < 8; ++j) v[j] = 0.0f;
    } else {
        const float4* cp = (const float4*)(csum + ((size_t)(b * NCH + k + 1)) * NC + cbase);
        float4 c0 = cp[0], c1 = cp[1];
        v[0]=c0.x; v[1]=c0.y; v[2]=c0.z; v[3]=c0.w;
        v[4]=c1.x; v[5]=c1.y; v[6]=c1.z; v[7]=c1.w;
    }

    // depth-1 prefetch of pred
    float4 np0, np1;
    {
        const float4* pp4 = (const float4*)(pred + ((size_t)b * NS + s0 + CL - 1) * NC + cbase);
        np0 = pp4[0]; np1 = pp4[1];
    }

    float acc = 0.0f;
    for (int i = CL - 1; i >= 0; --i) {
        const int s = s0 + i;
        float4 p0 = np0, p1 = np1;
        if (i > 0) {
            const float4* pp4 = (const float4*)(pred + ((size_t)b * NS + s - 1) * NC + cbase);
            np0 = pp4[0]; np1 = pp4[1];
        }

        // scan update: r[s] = a[s] + decay[s]*r[s+1];  r[0] := a[0] (d=0)
        const float d   = (s == 0) ? 0.0f : sh_dec[i];
        const float pv  = sh_p[i];
        const int   loc = ((wv < 2) ? sh_h[i] : sh_w[i]) - cbase;
        const float amt = ((wv & 1) == 0) ? (1.0f - pv) : pv;
#pragma unroll
        for (int j = 0; j < 8; ++j)
            v[j] = v[j] * d + ((loc == j) ? amt : 0.0f);

        float pd[8] = {p0.x, p0.y, p0.z, p0.w, p1.x, p1.y, p1.z, p1.w};

        // wave-local (segment-local) reductions
        float mr = v[0], mp = pd[0];
#pragma unroll
        for (int j = 1; j < 8; ++j) { mr = fmaxf(mr, v[j]); mp = fmaxf(mp, pd[j]); }
#pragma unroll
        for (int off = 32; off > 0; off >>= 1) {
            mr = fmaxf(mr, __shfl_xor(mr, off, 64));
            mp = fmaxf(mp, __shfl_xor(mp, off, 64));
        }
        float ser = 0.0f, dot = 0.0f, sep = 0.0f;
#pragma unroll
        for (int j = 0; j < 8; ++j) {
            float e = __expf(v[j] - mr);
            ser += e;
            dot = fmaf(e, pd[j], dot);
            sep += __expf(pd[j] - mp);
        }
#pragma unroll
        for (int off = 32; off > 0; off >>= 1) {
            ser += __shfl_xor(ser, off, 64);
            dot += __shfl_xor(dot, off, 64);
            sep += __shfl_xor(sep, off, 64);
        }
        const float lseg = (mp + __logf(sep)) - dot / ser;
        acc += lseg * (((wv & 1) == 0) ? (1.0f - pv) : pv);
    }

    if (ln == 0) sh_part[wv] = acc;   // acc is wave-uniform after reductions
    __syncthreads();
    if (tid == 0) {
        float tot = (sh_part[0] + sh_part[1] + sh_part[2] + sh_part[3])
                    * (1.0f / ((float)NB * (float)NS));
        atomicAdd(out, tot);
    }
}

// ---------------------------------------------------------------------------
extern "C" void kernel_launch(void* const* d_in, const int* in_sizes, int n_in,
                              void* d_out, int out_size, void* d_ws, size_t ws_size,
                              hipStream_t stream)
{
    const float* pred   = (const float*)d_in[0];
    const float* target = (const float*)d_in[1];
    float* out  = (float*)d_out;
    float* csum = (float*)d_ws;   // NB*NCH*NC floats = 4 MiB

    hipMemsetAsync(d_out, 0, sizeof(float), stream);
    tdl_chunksum_kernel<<<NB * NCH, 256, 0, stream>>>(target, csum);
    tdl_chunkscan_kernel<<<(NB * NC) / 256, 256, 0, stream>>>(target, csum);
    tdl_loss_kernel<<<NB * NCH, 256, 0, stream>>>(pred, target, csum, out);
}

// Round 2
// 66.817 us; speedup vs baseline: 1.2887x; 1.2887x over previous
//
#include <hip/hip_runtime.h>
#include <math.h>

#define NH 512
#define NW 512
#define NC 2048            // 2H + 2W
#define NB 4
#define NS 4096
#define INV_TEMP (1.0f / 256.0f)
#define CL 16              // chunk length
#define NCH (NS / CL)      // 256 chunks per batch

// ---------------------------------------------------------------------------
// Phase 1a: per-chunk local suffix scan (zero carry) + per-chunk alpha.
// csum[b,k,c]  = sum_{s in chunk k} a[b,s,c] * prod of decays within chunk
// alpha[b,k]   = prod of decays over chunk k  (0 for the last chunk)
// One block per (b,k); 4 waves own the 4 segments, 8 channels/lane.
// ---------------------------------------------------------------------------
__global__ __launch_bounds__(256) void tdl_chunksum_kernel(
    const float* __restrict__ target, float* __restrict__ csum,
    float* __restrict__ alpha)
{
    const int blk = blockIdx.x;
    const int b = blk >> 8;          // / NCH
    const int k = blk & (NCH - 1);
    const int s0 = k * CL;
    const int tid = threadIdx.x;

    __shared__ float sh_t[CL + 1];
    __shared__ float sh_dec[CL];
    __shared__ int   sh_h[CL];
    __shared__ int   sh_w[CL];
    __shared__ float sh_p[CL];

    if (tid <= CL) {
        int s = s0 + tid;
        sh_t[tid] = (s < NS) ? target[((size_t)b * NS + s) * 4] : 0.0f;
    }
    if (tid < CL) {
        const float* tg = target + ((size_t)b * NS + s0 + tid) * 4;
        sh_h[tid] = (int)tg[1];
        sh_w[tid] = (int)tg[2];
        sh_p[tid] = tg[3];
    }
    __syncthreads();
    if (tid < CL) {
        int s = s0 + tid;
        sh_dec[tid] = (s == NS - 1) ? 0.0f
                     : __expf(-(sh_t[tid + 1] - sh_t[tid]) * INV_TEMP);
    }
    if (tid == 0) {
        alpha[b * NCH + k] = (k == NCH - 1) ? 0.0f
                            : __expf(-(sh_t[CL] - sh_t[0]) * INV_TEMP);
    }
    __syncthreads();

    const int wv = tid >> 6;         // wave -> segment (0..3)
    const int ln = tid & 63;
    const int cbase = wv * 512 + ln * 8;

    float v[8];
#pragma unroll
    for (int j = 0; j < 8; ++j) v[j] = 0.0f;

    for (int i = CL - 1; i >= 0; --i) {
        const float d   = sh_dec[i];
        const float pv  = sh_p[i];
        const int   loc = ((wv < 2) ? sh_h[i] : sh_w[i]) - cbase;
        const float amt = ((wv & 1) == 0) ? (1.0f - pv) : pv;
#pragma unroll
        for (int j = 0; j < 8; ++j)
            v[j] = v[j] * d + ((loc == j) ? amt : 0.0f);
    }

    float4* o4 = (float4*)(csum + (size_t)blk * NC + cbase);
    o4[0] = make_float4(v[0], v[1], v[2], v[3]);
    o4[1] = make_float4(v[4], v[5], v[6], v[7]);
}

// ---------------------------------------------------------------------------
// Phase 1b: cross-chunk reverse scan.  rstart[b,k,c] = r[b, k*CL, c].
// Separate in/out buffers + __restrict__ so the 256 loads pipeline ahead of
// the serial carry FMA chain.  alpha loads are wave-uniform -> scalar.
// ---------------------------------------------------------------------------
__global__ __launch_bounds__(256) void tdl_chunkscan_kernel(
    const float* __restrict__ csum, const float* __restrict__ alpha,
    float* __restrict__ rstart)
{
    const int gtid = blockIdx.x * 256 + threadIdx.x;   // [0, NB*NC)
    const int b = gtid >> 11;        // / NC
    const int c = gtid & (NC - 1);

    const float* cs = csum   + (size_t)b * NCH * NC + c;
    float*       rs = rstart + (size_t)b * NCH * NC + c;
    const float* al = alpha  + b * NCH;

    float carry = 0.0f;
#pragma unroll 8
    for (int k = NCH - 1; k >= 0; --k) {
        carry = cs[(size_t)k * NC] + al[k] * carry;
        rs[(size_t)k * NC] = carry;
    }
}

// ---------------------------------------------------------------------------
// Phase 2: fused scan + soft-CE loss. One block per (b,k); incoming carry is
// rstart[b,k+1,:]. Wave w owns segment w (512 ch = 64 lanes x 8).
//   lseg = log(sum exp(pred_seg)) - dot(softmax(r_seg), pred_seg)
// (no max-shift: pred ~ N(0,1), r in [0, ~2] -> exp safe in fp32)
// ---------------------------------------------------------------------------
__global__ __launch_bounds__(256) void tdl_loss_kernel(
    const float* __restrict__ pred, const float* __restrict__ target,
    const float* __restrict__ rstart, float* __restrict__ out)
{
    const int blk = blockIdx.x;
    const int b = blk >> 8;
    const int k = blk & (NCH - 1);
    const int s0 = k * CL;
    const int tid = threadIdx.x;

    __shared__ float sh_t[CL + 1];
    __shared__ float sh_dec[CL];
    __shared__ int   sh_h[CL];
    __shared__ int   sh_w[CL];
    __shared__ float sh_p[CL];
    __shared__ float sh_part[4];

    if (tid <= CL) {
        int s = s0 + tid;
        sh_t[tid] = (s < NS) ? target[((size_t)b * NS + s) * 4] : 0.0f;
    }
    if (tid < CL) {
        const float* tg = target + ((size_t)b * NS + s0 + tid) * 4;
        sh_h[tid] = (int)tg[1];
        sh_w[tid] = (int)tg[2];
        sh_p[tid] = tg[3];
    }
    __syncthreads();
    if (tid < CL) {
        int s = s0 + tid;
        sh_dec[tid] = (s == NS - 1) ? 0.0f
                     : __expf(-(sh_t[tid + 1] - sh_t[tid]) * INV_TEMP);
    }
    __syncthreads();

    const int wv = tid >> 6;
    const int ln = tid & 63;
    const int cbase = wv * 512 + ln * 8;

    // incoming carry = r[b, (k+1)*CL, :]  (zero for the last chunk)
    float v[8];
    if (k == NCH - 1) {
#pragma unroll
        for (int j = 0; j < 8; ++j) v[j] = 0.0f;
    } else {
        const float4* cp = (const float4*)(rstart + ((size_t)(b * NCH + k + 1)) * NC + cbase);
        float4 c0 = cp[0], c1 = cp[1];
        v[0]=c0.x; v[1]=c0.y; v[2]=c0.z; v[3]=c0.w;
        v[4]=c1.x; v[5]=c1.y; v[6]=c1.z; v[7]=c1.w;
    }

    // depth-1 prefetch of pred
    float4 np0, np1;
    {
        const float4* pp4 = (const float4*)(pred + ((size_t)b * NS + s0 + CL - 1) * NC + cbase);
        np0 = pp4[0]; np1 = pp4[1];
    }

    float acc = 0.0f;
    for (int i = CL - 1; i >= 0; --i) {
        const int s = s0 + i;
        float4 p0 = np0, p1 = np1;
        if (i > 0) {
            const float4* pp4 = (const float4*)(pred + ((size_t)b * NS + s - 1) * NC + cbase);
            np0 = pp4[0]; np1 = pp4[1];
        }

        // scan update: r[s] = a[s] + decay[s]*r[s+1];  r[0] := a[0] (d=0)
        const float d   = (s == 0) ? 0.0f : sh_dec[i];
        const float pv  = sh_p[i];
        const int   loc = ((wv < 2) ? sh_h[i] : sh_w[i]) - cbase;
        const float amt = ((wv & 1) == 0) ? (1.0f - pv) : pv;
#pragma unroll
        for (int j = 0; j < 8; ++j)
            v[j] = v[j] * d + ((loc == j) ? amt : 0.0f);

        const float pd[8] = {p0.x, p0.y, p0.z, p0.w, p1.x, p1.y, p1.z, p1.w};

        float ser = 0.0f, dot = 0.0f, sep = 0.0f;
#pragma unroll
        for (int j = 0; j < 8; ++j) {
            float e = __expf(v[j]);
            ser += e;
            dot = fmaf(e, pd[j], dot);
            sep += __expf(pd[j]);
        }
#pragma unroll
        for (int off = 32; off > 0; off >>= 1) {
            ser += __shfl_xor(ser, off, 64);
            dot += __shfl_xor(dot, off, 64);
            sep += __shfl_xor(sep, off, 64);
        }
        const float lseg = __logf(sep) - dot / ser;
        acc += lseg * (((wv & 1) == 0) ? (1.0f - pv) : pv);
    }

    if (ln == 0) sh_part[wv] = acc;   // acc is wave-uniform after reductions
    __syncthreads();
    if (tid == 0) {
        float tot = (sh_part[0] + sh_part[1] + sh_part[2] + sh_part[3])
                    * (1.0f / ((float)NB * (float)NS));
        atomicAdd(out, tot);
    }
}

// ---------------------------------------------------------------------------
extern "C" void kernel_launch(void* const* d_in, const int* in_sizes, int n_in,
                              void* d_out, int out_size, void* d_ws, size_t ws_size,
                              hipStream_t stream)
{
    const float* pred   = (const float*)d_in[0];
    const float* target = (const float*)d_in[1];
    float* out = (float*)d_out;

    float* csum   = (float*)d_ws;                          // NB*NCH*NC = 8 MiB
    float* rstart = csum + (size_t)NB * NCH * NC;          // 8 MiB
    float* alpha  = rstart + (size_t)NB * NCH * NC;        // 4 KiB

    hipMemsetAsync(d_out, 0, sizeof(float), stream);
    tdl_chunksum_kernel<<<NB * NCH, 256, 0, stream>>>(target, csum, alpha);
    tdl_chunkscan_kernel<<<(NB * NC) / 256, 256, 0, stream>>>(csum, alpha, rstart);
    tdl_loss_kernel<<<NB * NCH, 256, 0, stream>>>(pred, target, rstart, out);
}

// Round 4
// 59.302 us; speedup vs baseline: 1.4520x; 1.1267x over previous
//
#include <hip/hip_runtime.h>
#include <math.h>

#define NH 512
#define NW 512
#define NC 2048            // 2H + 2W
#define NB 4
#define NS 4096
#define INV_TEMP (1.0f / 256.0f)
#define CL 16              // chunk length
#define NCH (NS / CL)      // 256 chunks per batch
#define NG 8               // scan groups per (b,c)
#define GK (NCH / NG)      // 32 chunks per group

typedef float f32x4 __attribute__((ext_vector_type(4)));

// ---------------------------------------------------------------------------
// Phase 1a: per-chunk local suffix scan (zero carry) + per-chunk alpha.
// csum[b,k,c]  = sum_{s in chunk k} a[b,s,c] * prod of in-chunk decays
// alpha[b,k]   = decay product bridging chunk k -> k+1  (0 for last chunk)
// One block per (b,k); 4 waves own the 4 segments, 8 channels/lane.
// ---------------------------------------------------------------------------
__global__ __launch_bounds__(256) void tdl_chunksum_kernel(
    const float* __restrict__ target, float* __restrict__ csum,
    float* __restrict__ alpha)
{
    const int blk = blockIdx.x;
    const int b = blk >> 8;          // / NCH
    const int k = blk & (NCH - 1);
    const int s0 = k * CL;
    const int tid = threadIdx.x;

    __shared__ float sh_t[CL + 1];
    __shared__ float sh_dec[CL];
    __shared__ int   sh_h[CL];
    __shared__ int   sh_w[CL];
    __shared__ float sh_p[CL];

    if (tid <= CL) {
        int s = s0 + tid;
        sh_t[tid] = (s < NS) ? target[((size_t)b * NS + s) * 4] : 0.0f;
    }
    if (tid < CL) {
        const float* tg = target + ((size_t)b * NS + s0 + tid) * 4;
        sh_h[tid] = (int)tg[1];
        sh_w[tid] = (int)tg[2];
        sh_p[tid] = tg[3];
    }
    __syncthreads();
    if (tid < CL) {
        int s = s0 + tid;
        sh_dec[tid] = (s == NS - 1) ? 0.0f
                     : __expf(-(sh_t[tid + 1] - sh_t[tid]) * INV_TEMP);
    }
    if (tid == 0) {
        alpha[b * NCH + k] = (k == NCH - 1) ? 0.0f
                            : __expf(-(sh_t[CL] - sh_t[0]) * INV_TEMP);
    }
    __syncthreads();

    const int wv = tid >> 6;         // wave -> segment (0..3)
    const int ln = tid & 63;
    const int cbase = wv * 512 + ln * 8;

    float v[8];
#pragma unroll
    for (int j = 0; j < 8; ++j) v[j] = 0.0f;

    for (int i = CL - 1; i >= 0; --i) {
        const float d   = sh_dec[i];
        const float pv  = sh_p[i];
        const int   loc = ((wv < 2) ? sh_h[i] : sh_w[i]) - cbase;
        const float amt = ((wv & 1) == 0) ? (1.0f - pv) : pv;
#pragma unroll
        for (int j = 0; j < 8; ++j)
            v[j] = v[j] * d + ((loc == j) ? amt : 0.0f);
    }

    float4* o4 = (float4*)(csum + (size_t)blk * NC + cbase);
    o4[0] = make_float4(v[0], v[1], v[2], v[3]);
    o4[1] = make_float4(v[4], v[5], v[6], v[7]);
}

// ---------------------------------------------------------------------------
// Phase 1b: hierarchical cross-chunk reverse scan.
// 8 threads per (b,c), each owning GK=32 chunks held in registers:
//   pass 1: local suffix scan with zero carry -> (L = value at group start,
//           G = product of group alphas)
//   LDS exchange of (L,G) across the 8 groups, serial 8-wide scan per thread
//   pass 2: replay with true incoming carry, store rstart.
// 256 blocks x 256 threads; all 32 loads per thread issued up front (ILP).
// ---------------------------------------------------------------------------
__global__ __launch_bounds__(256) void tdl_chunkscan_kernel(
    const float* __restrict__ csum, const float* __restrict__ alpha,
    float* __restrict__ rstart)
{
    const int tid = threadIdx.x;
    const int ci  = tid & 31;            // channel within 32-wide tile
    const int g   = tid >> 5;            // scan group (0..7)
    const int b     = blockIdx.x >> 6;   // / (NC/32)
    const int ctile = blockIdx.x & 63;
    const int c     = ctile * 32 + ci;

    const float* cs = csum   + ((size_t)(b * NCH + g * GK)) * NC + c;
    float*       rs = rstart + ((size_t)(b * NCH + g * GK)) * NC + c;
    const float* al = alpha  + b * NCH + g * GK;

    float v[GK];
    float a[GK];
#pragma unroll
    for (int i = 0; i < GK; ++i) v[i] = cs[(size_t)i * NC];
#pragma unroll
    for (int i = 0; i < GK; ++i) a[i] = al[i];

    // local suffix scan (zero incoming carry) + group transfer product
    float L = 0.0f, G = 1.0f;
#pragma unroll
    for (int i = GK - 1; i >= 0; --i) {
        L = fmaf(a[i], L, v[i]);
        G *= a[i];
    }

    __shared__ float shL[NG][32];
    __shared__ float shG[NG][32];
    shL[g][ci] = L;
    shG[g][ci] = G;
    __syncthreads();

    // carry into group g = suffix scan over groups g+1 .. NG-1
    float X = 0.0f;
#pragma unroll
    for (int j = NG - 1; j >= 1; --j) {
        if (j > g) X = fmaf(shG[j][ci], X, shL[j][ci]);
    }

    // replay with true carry and store
    float carry = X;
#pragma unroll
    for (int i = GK - 1; i >= 0; --i) {
        carry = fmaf(a[i], carry, v[i]);
        rs[(size_t)i * NC] = carry;
    }
}

// ---------------------------------------------------------------------------
// Phase 2: fused scan + soft-CE loss. One block per (b,k); incoming carry is
// rstart[b,k+1,:]. Wave w owns segment w (512 ch = 64 lanes x 8).
//   lseg = log(sum exp(pred_seg)) - dot(softmax(r_seg), pred_seg)
// (no max-shift: pred ~ N(0,1), r in [0,~2] -> exp safe in fp32)
// ---------------------------------------------------------------------------
__global__ __launch_bounds__(256) void tdl_loss_kernel(
    const float* __restrict__ pred, const float* __restrict__ target,
    const float* __restrict__ rstart, float* __restrict__ out)
{
    const int blk = blockIdx.x;
    const int b = blk >> 8;
    const int k = blk & (NCH - 1);
    const int s0 = k * CL;
    const int tid = threadIdx.x;

    __shared__ float sh_t[CL + 1];
    __shared__ float sh_dec[CL];
    __shared__ int   sh_h[CL];
    __shared__ int   sh_w[CL];
    __shared__ float sh_p[CL];
    __shared__ float sh_part[4];

    if (tid <= CL) {
        int s = s0 + tid;
        sh_t[tid] = (s < NS) ? target[((size_t)b * NS + s) * 4] : 0.0f;
    }
    if (tid < CL) {
        const float* tg = target + ((size_t)b * NS + s0 + tid) * 4;
        sh_h[tid] = (int)tg[1];
        sh_w[tid] = (int)tg[2];
        sh_p[tid] = tg[3];
    }
    __syncthreads();
    if (tid < CL) {
        int s = s0 + tid;
        sh_dec[tid] = (s == NS - 1) ? 0.0f
                     : __expf(-(sh_t[tid + 1] - sh_t[tid]) * INV_TEMP);
    }
    __syncthreads();

    const int wv = tid >> 6;
    const int ln = tid & 63;
    const int cbase = wv * 512 + ln * 8;

    // incoming carry = r[b, (k+1)*CL, :]  (zero for the last chunk)
    float v[8];
    if (k == NCH - 1) {
#pragma unroll
        for (int j = 0; j < 8; ++j) v[j] = 0.0f;
    } else {
        const float4* cp = (const float4*)(rstart + ((size_t)(b * NCH + k + 1)) * NC + cbase);
        float4 c0 = cp[0], c1 = cp[1];
        v[0]=c0.x; v[1]=c0.y; v[2]=c0.z; v[3]=c0.w;
        v[4]=c1.x; v[5]=c1.y; v[6]=c1.z; v[7]=c1.w;
    }

    // depth-1 prefetch of pred (nontemporal: read-once stream)
    const f32x4* pbase = (const f32x4*)(pred + ((size_t)b * NS) * NC + cbase);
    f32x4 np0, np1;
    {
        const f32x4* pp4 = pbase + (size_t)(s0 + CL - 1) * (NC / 4);
        np0 = __builtin_nontemporal_load(pp4);
        np1 = __builtin_nontemporal_load(pp4 + 1);
    }

    float acc = 0.0f;
    for (int i = CL - 1; i >= 0; --i) {
        const int s = s0 + i;
        f32x4 p0 = np0, p1 = np1;
        if (i > 0) {
            const f32x4* pp4 = pbase + (size_t)(s - 1) * (NC / 4);
            np0 = __builtin_nontemporal_load(pp4);
            np1 = __builtin_nontemporal_load(pp4 + 1);
        }

        // scan update: r[s] = a[s] + decay[s]*r[s+1];  r[0] := a[0] (d=0)
        const float d   = (s == 0) ? 0.0f : sh_dec[i];
        const float pv  = sh_p[i];
        const int   loc = ((wv < 2) ? sh_h[i] : sh_w[i]) - cbase;
        const float amt = ((wv & 1) == 0) ? (1.0f - pv) : pv;
#pragma unroll
        for (int j = 0; j < 8; ++j)
            v[j] = v[j] * d + ((loc == j) ? amt : 0.0f);

        const float pd[8] = {p0.x, p0.y, p0.z, p0.w, p1.x, p1.y, p1.z, p1.w};

        float ser = 0.0f, dot = 0.0f, sep = 0.0f;
#pragma unroll
        for (int j = 0; j < 8; ++j) {
            float e = __expf(v[j]);
            ser += e;
            dot = fmaf(e, pd[j], dot);
            sep += __expf(pd[j]);
        }
#pragma unroll
        for (int off = 32; off > 0; off >>= 1) {
            ser += __shfl_xor(ser, off, 64);
            dot += __shfl_xor(dot, off, 64);
            sep += __shfl_xor(sep, off, 64);
        }
        const float lseg = __logf(sep) - dot / ser;
        acc += lseg * (((wv & 1) == 0) ? (1.0f - pv) : pv);
    }

    if (ln == 0) sh_part[wv] = acc;   // acc is wave-uniform after reductions
    __syncthreads();
    if (tid == 0) {
        float tot = (sh_part[0] + sh_part[1] + sh_part[2] + sh_part[3])
                    * (1.0f / ((float)NB * (float)NS));
        atomicAdd(out, tot);
    }
}

// ---------------------------------------------------------------------------
extern "C" void kernel_launch(void* const* d_in, const int* in_sizes, int n_in,
                              void* d_out, int out_size, void* d_ws, size_t ws_size,
                              hipStream_t stream)
{
    const float* pred   = (const float*)d_in[0];
    const float* target = (const float*)d_in[1];
    float* out = (float*)d_out;

    float* csum   = (float*)d_ws;                          // NB*NCH*NC = 8 MiB
    float* rstart = csum + (size_t)NB * NCH * NC;          // 8 MiB
    float* alpha  = rstart + (size_t)NB * NCH * NC;        // 4 KiB

    (void)hipMemsetAsync(d_out, 0, sizeof(float), stream);
    tdl_chunksum_kernel<<<NB * NCH, 256, 0, stream>>>(target, csum, alpha);
    tdl_chunkscan_kernel<<<NB * (NC / 32), 256, 0, stream>>>(csum, alpha, rstart);
    tdl_loss_kernel<<<NB * NCH, 256, 0, stream>>>(pred, target, rstart, out);
}

// Round 5
// 47.494 us; speedup vs baseline: 1.8130x; 1.2486x over previous
//
#include <hip/hip_runtime.h>
#include <math.h>

#define NC 2048            // 2H + 2W (H = W = 512)
#define NB 4
#define NS 4096
#define INV_TEMP (1.0f / 256.0f)
#define CL 16              // chunk length (loss-kernel granularity)
#define NCH (NS / CL)      // 256 chunks per batch
#define P1_NG 16           // scan groups per P1 block (512 thr / 32 ch)
#define P1_GS (NS / P1_NG) // 256 s per group
#define P1_GC (P1_GS / CL) // 16 chunks per group

typedef float f32x4 __attribute__((ext_vector_type(4)));

// ---------------------------------------------------------------------------
// Phase 1 (merged): per-(b, 32-channel tile) block.
//  - stage target[b] (4096 x {t,h,w,p}) in LDS, overwrite t with per-step dec
//  - each thread (group g, channel ci) computes its 16 per-chunk csums and
//    chunk alphas IN REGISTERS (alphas telescope from t endpoints)
//  - hierarchical suffix scan: group-local combine -> LDS exchange of (L,G)
//    across 16 groups -> replay with true carry, storing rstart[b,k,c]
//  Replaces old chunksum+chunkscan kernels and the memset (block 0 zeroes out).
// ---------------------------------------------------------------------------
__global__ __launch_bounds__(512) void tdl_scan_kernel(
    const float* __restrict__ target, float* __restrict__ rstart,
    float* __restrict__ out)
{
    const int b     = blockIdx.x >> 6;   // 64 channel-tiles per batch
    const int ctile = blockIdx.x & 63;
    const int tid = threadIdx.x;
    const int ci  = tid & 31;            // channel within tile
    const int g   = tid >> 5;            // scan group (0..15)

    if (blockIdx.x == 0 && tid == 0) out[0] = 0.0f;  // zero loss accumulator

    __shared__ f32x4 ev[NS];             // {t -> dec, h, w, p}
    __shared__ float shL[P1_NG][32];
    __shared__ float shG[P1_NG];

    const float* tb = target + (size_t)b * NS * 4;

    // 1. cooperative stage of target[b] (AoS float4 == {t,h,w,p})
#pragma unroll
    for (int m = 0; m < NS / 512; ++m) {
        int s = m * 512 + tid;
        ev[s] = *((const f32x4*)tb + s);
    }
    __syncthreads();

    // 2. per-step dec (8/thread) + my 16 chunk-alphas + group G, all from t
    float decv[8];
#pragma unroll
    for (int m = 0; m < 8; ++m) {
        int s = m * 512 + tid;
        decv[m] = (s == NS - 1) ? 0.0f
                 : __expf(-(ev[s + 1].x - ev[s].x) * INV_TEMP);
    }
    float alp[P1_GC];
    {
        const int gs = g * P1_GS;
#pragma unroll
        for (int q = 0; q < P1_GC; ++q) {
            int se = gs + q * CL;
            alp[q] = (g == P1_NG - 1 && q == P1_GC - 1) ? 0.0f
                     : __expf(-(ev[se + CL].x - ev[se].x) * INV_TEMP);
        }
        if (ci == 0) {
            shG[g] = (g == P1_NG - 1) ? 0.0f
                     : __expf(-(ev[gs + P1_GS].x - ev[gs].x) * INV_TEMP);
        }
    }
    __syncthreads();

    // 3. overwrite t with dec
#pragma unroll
    for (int m = 0; m < 8; ++m) ev[m * 512 + tid].x = decv[m];
    __syncthreads();

    // 4. per-chunk local suffix sums (zero carry), 16 chunks in registers
    const int  seg  = ctile >> 4;                       // 0..3
    const float crel = (float)(((ctile & 15) << 5) + ci); // in-segment channel
    const bool useH = (seg < 2);
    const bool odd  = (seg & 1);

    float cs[P1_GC];
    {
        const int gs = g * P1_GS;
#pragma unroll
        for (int q = P1_GC - 1; q >= 0; --q) {
            float v = 0.0f;
            const int base = gs + q * CL;
#pragma unroll
            for (int i = CL - 1; i >= 0; --i) {
                f32x4 e = ev[base + i];
                float idx = useH ? e.y : e.z;
                float amt = odd ? e.w : (1.0f - e.w);
                v = fmaf(v, e.x, (idx == crel) ? amt : 0.0f);
            }
            cs[q] = v;
        }
    }

    // 5. group-local combine -> L (value at group start, zero incoming)
    float L = 0.0f;
#pragma unroll
    for (int q = P1_GC - 1; q >= 0; --q) L = fmaf(alp[q], L, cs[q]);
    shL[g][ci] = L;
    __syncthreads();

    // 6. carry into group g = suffix over groups j > g
    float X = 0.0f;
#pragma unroll
    for (int j = P1_NG - 1; j >= 1; --j)
        if (j > g) X = fmaf(shG[j], X, shL[j][ci]);

    // 7. chunk-level replay with carry, store rstart[b, g*16+q, c]
    float* rs = rstart + ((size_t)b * NCH + g * P1_GC) * NC + (ctile * 32 + ci);
    float carry = X;
#pragma unroll
    for (int q = P1_GC - 1; q >= 0; --q) {
        carry = fmaf(alp[q], carry, cs[q]);
        rs[(size_t)q * NC] = carry;
    }
}

// ---------------------------------------------------------------------------
// Phase 2: fused scan + soft-CE loss. One block (128 thr = 2 waves) per (b,k).
// Wave 0 handles segments H0|H1 (lanes 0-31 | 32-63), wave 1 handles W0|W1.
// Each lane owns 16 channels of its segment via q-strided mapping
//   channel = seg*512 + q*128 + lnn*4 + j   (q,j in 0..3)
// so every pred/rstart load instr is 512 B contiguous per half-wave.
// Reductions span 32 lanes (5 shfl levels; xor offsets <32 stay in-half).
//   lseg = log(sum exp(pred)) - dot(softmax(r), pred);  acc += lseg * weight
// ---------------------------------------------------------------------------
__global__ __launch_bounds__(128) void tdl_loss_kernel(
    const float* __restrict__ pred, const float* __restrict__ target,
    const float* __restrict__ rstart, float* __restrict__ out)
{
    const int blk = blockIdx.x;
    const int b = blk >> 8;              // / NCH
    const int k = blk & (NCH - 1);
    const int s0 = k * CL;
    const int tid = threadIdx.x;
    const int wv   = tid >> 6;           // 0: H-pair, 1: W-pair
    const int ln   = tid & 63;
    const int half = ln >> 5;            // 0 / 1 within wave
    const int lnn  = ln & 31;
    const int seg  = (wv << 1) | half;   // 0..3

    __shared__ f32x4 ev[CL];             // {dec, p, h, w}
    __shared__ float sh4[4];

    if (tid < CL) {
        const float* tg = target + ((size_t)b * NS + s0 + tid) * 4;
        float t0 = tg[0], h = tg[1], w = tg[2], p = tg[3];
        int s = s0 + tid;
        float dec = (s == NS - 1 || s == 0) ? 0.0f
                   : __expf(-(tg[4] - t0) * INV_TEMP);   // tg[4] = t[s+1]
        f32x4 e; e.x = dec; e.y = p; e.z = h; e.w = w;
        ev[tid] = e;
    }
    __syncthreads();

    const int coff = seg * 512 + lnn * 4;          // channel of (q=0, j=0)
    const float* prow = pred + (size_t)b * NS * NC + coff;

    // carry init = r[b, (k+1)*CL, my channels] (zero for last chunk)
    float vv[16];
    if (k == NCH - 1) {
#pragma unroll
        for (int j = 0; j < 16; ++j) vv[j] = 0.0f;
    } else {
        const float* rrow = rstart + ((size_t)b * NCH + k + 1) * NC + coff;
#pragma unroll
        for (int q = 0; q < 4; ++q) {
            f32x4 r = *(const f32x4*)(rrow + q * 128);
            vv[q*4+0] = r.x; vv[q*4+1] = r.y; vv[q*4+2] = r.z; vv[q*4+3] = r.w;
        }
    }

    // depth-1 prefetch of pred (plain loads: pred fits L3, keep it resident)
    f32x4 np[4];
    {
        const float* pr = prow + (size_t)(s0 + CL - 1) * NC;
#pragma unroll
        for (int q = 0; q < 4; ++q) np[q] = *(const f32x4*)(pr + q * 128);
    }

    const float fj0 = (float)(lnn * 4);
    float acc = 0.0f;

    for (int i = CL - 1; i >= 0; --i) {
        f32x4 cur[4];
#pragma unroll
        for (int q = 0; q < 4; ++q) cur[q] = np[q];
        if (i > 0) {
            const float* pr = prow + (size_t)(s0 + i - 1) * NC;
#pragma unroll
            for (int q = 0; q < 4; ++q) np[q] = *(const f32x4*)(pr + q * 128);
        }

        f32x4 e = ev[i];
        const float d    = e.x;
        const float p    = e.y;
        const float idxf = wv ? e.w : e.z;          // w for W-pair, h for H-pair
        const float amt  = half ? p : (1.0f - p);   // also the segment weight

        float ser = 0.0f, dot = 0.0f, sep = 0.0f;
#pragma unroll
        for (int q = 0; q < 4; ++q) {
            const float basef = (float)(q * 128) + fj0;
#pragma unroll
            for (int j = 0; j < 4; ++j) {
                const int id = q * 4 + j;
                float add = (idxf == basef + (float)j) ? amt : 0.0f;
                vv[id] = fmaf(vv[id], d, add);      // r[s] = a + dec * r[s+1]
                float ex = __expf(vv[id]);
                ser += ex;
                float pj = cur[q][j];
                dot = fmaf(ex, pj, dot);
                sep += __expf(pj);
            }
        }
        // 32-lane (per-segment) reductions; xor offs < 32 stay within halves
#pragma unroll
        for (int off = 16; off > 0; off >>= 1) {
            ser += __shfl_xor(ser, off, 64);
            dot += __shfl_xor(dot, off, 64);
            sep += __shfl_xor(sep, off, 64);
        }
        acc += (__logf(sep) - dot / ser) * amt;
    }

    if (lnn == 0) sh4[seg] = acc;   // acc is half-uniform; one writer per seg
    __syncthreads();
    if (tid == 0) {
        float tot = (sh4[0] + sh4[1] + sh4[2] + sh4[3])
                    * (1.0f / ((float)NB * (float)NS));
        atomicAdd(out, tot);
    }
}

// ---------------------------------------------------------------------------
extern "C" void kernel_launch(void* const* d_in, const int* in_sizes, int n_in,
                              void* d_out, int out_size, void* d_ws, size_t ws_size,
                              hipStream_t stream)
{
    const float* pred   = (const float*)d_in[0];
    const float* target = (const float*)d_in[1];
    float* out    = (float*)d_out;
    float* rstart = (float*)d_ws;   // NB*NCH*NC floats = 8 MiB

    tdl_scan_kernel<<<NB * 64, 512, 0, stream>>>(target, rstart, out);
    tdl_loss_kernel<<<NB * NCH, 128, 0, stream>>>(pred, target, rstart, out);
}